// Round 1
// baseline (506.669 us; speedup 1.0000x reference)
//
#include <hip/hip_runtime.h>
#include <math.h>

// Problem constants (B=16, H=W=128, C=256, PATCH=8)
#define CCH   256      // channels
#define HID   64       // hidden dim of scorer MLP
#define MT    256      // tokens per block in scorer kernel
#define KC    32       // K-chunk staged in LDS
#define XT    258      // padded row stride (dwords) for k-major x tile
#define NP    256      // patches per image (16x16)
#define NK    179      // kept patches: max(10, int(256*0.7))
#define NSLOT 192      // 12*16 output patch grid slots
#define IMW   128      // image width (tokens)
#define OUTH  96       // output height (12*8)

// ---------------- Kernel 1: token scorer (fused 2-layer MLP) ----------------
// grid = totalTokens/MT blocks, 256 threads. Each thread: 8 tokens x 8 hidden.
__global__ __launch_bounds__(256) void scorer_kernel(
    const float* __restrict__ tokens, const float* __restrict__ W1,
    const float* __restrict__ b1, const float* __restrict__ W2,
    const float* __restrict__ b2v, float* __restrict__ tok_imp)
{
    __shared__ float xs[KC * XT];        // x chunk, k-major: xs[k][tok], 33 KB
    __shared__ float ws[KC * HID];       // W1 chunk: ws[k][h], 8 KB
    __shared__ float red[8 * MT];        // layer-2 partial reduction, 8 KB

    const int t  = threadIdx.x;
    const int tw = t & 31;               // token lane group (tokens tw + 32*i)
    const int hg = t >> 5;               // hidden group (hidden hg*8 .. +7)
    const long base = (long)blockIdx.x * MT;   // global token id base

    float w2r[8];
    float acc[8][8];
    #pragma unroll
    for (int j = 0; j < 8; ++j) w2r[j] = W2[hg * 8 + j];
    {
        float binit[8];
        #pragma unroll
        for (int j = 0; j < 8; ++j) binit[j] = b1[hg * 8 + j];
        #pragma unroll
        for (int i = 0; i < 8; ++i)
            #pragma unroll
            for (int j = 0; j < 8; ++j) acc[i][j] = binit[j];
    }

    const float4* tok4 = (const float4*)(tokens + base * CCH);
    const int f4k = t & 7;       // which float4 of the 32-float k-chunk
    const int tl0 = t >> 3;      // token row 0..31 per pass

    for (int ch = 0; ch < CCH / KC; ++ch) {
        // ---- stage x chunk (transposed to k-major) ----
        #pragma unroll
        for (int pass = 0; pass < 8; ++pass) {
            int tokLocal = tl0 + 32 * pass;
            float4 v = tok4[(long)tokLocal * (CCH / 4) + ch * (KC / 4) + f4k];
            int kloc = f4k * 4;
            xs[(kloc + 0) * XT + tokLocal] = v.x;
            xs[(kloc + 1) * XT + tokLocal] = v.y;
            xs[(kloc + 2) * XT + tokLocal] = v.z;
            xs[(kloc + 3) * XT + tokLocal] = v.w;
        }
        // ---- stage W1 chunk (contiguous 2048 floats) ----
        {
            const float4* w14 = (const float4*)(W1 + ch * KC * HID);
            ((float4*)ws)[t]       = w14[t];
            ((float4*)ws)[t + 256] = w14[t + 256];
        }
        __syncthreads();
        // ---- FMA inner loop ----
        #pragma unroll
        for (int kk = 0; kk < KC; ++kk) {
            float xv[8], wv[8];
            #pragma unroll
            for (int i = 0; i < 8; ++i) xv[i] = xs[kk * XT + 32 * i + tw];
            #pragma unroll
            for (int j = 0; j < 8; ++j) wv[j] = ws[kk * HID + hg * 8 + j];
            #pragma unroll
            for (int i = 0; i < 8; ++i)
                #pragma unroll
                for (int j = 0; j < 8; ++j)
                    acc[i][j] = fmaf(xv[i], wv[j], acc[i][j]);
        }
        __syncthreads();
    }

    // ---- layer 2: relu(h) . W2, partial per hidden-group ----
    #pragma unroll
    for (int i = 0; i < 8; ++i) {
        float p = 0.f;
        #pragma unroll
        for (int j = 0; j < 8; ++j) {
            float h = acc[i][j] > 0.f ? acc[i][j] : 0.f;
            p = fmaf(h, w2r[j], p);
        }
        red[hg * MT + tw + 32 * i] = p;
    }
    __syncthreads();
    float s = b2v[0];
    #pragma unroll
    for (int g = 0; g < 8; ++g) s += red[g * MT + t];
    tok_imp[base + t] = 1.f / (1.f + expf(-s));
}

// ---------------- Kernel 2: per-batch patch scores + stable top-k ----------
// grid = B blocks, 256 threads (one per patch).
__global__ __launch_bounds__(256) void select_kernel(
    const float* __restrict__ tok_imp, int* __restrict__ sel)
{
    __shared__ float s[NP];
    __shared__ int flag[NP];
    const int b = blockIdx.x, p = threadIdx.x;
    const int ih = p >> 4, iw = p & 15;
    const float* tp = tok_imp + (long)b * 16384 + (ih * 8) * IMW + iw * 8;
    float sum = 0.f;
    #pragma unroll
    for (int ti = 0; ti < 8; ++ti)
        #pragma unroll
        for (int tj = 0; tj < 8; ++tj)
            sum += tp[ti * IMW + tj];
    s[p] = sum;                      // mean = sum/64: monotone, rank-identical
    __syncthreads();
    const float sp = s[p];
    int rank = 0;
    for (int j = 0; j < NP; ++j) {
        float sj = s[j];
        rank += (sj > sp) || ((sj == sp) && (j < p));   // stable top_k order
    }
    flag[p] = (rank < NK) ? 1 : 0;
    __syncthreads();
    if (rank < NK) {
        int pos = 0;
        for (int j = 0; j < p; ++j) pos += flag[j];
        sel[b * NK + pos] = p;       // selected patches in ascending index order
    }
}

// ---------------- Kernel 3: gather kept patches into output grid -----------
// grid = B*NSLOT blocks, 256 threads; each block moves one 64 KB patch.
__global__ __launch_bounds__(256) void gather_kernel(
    const float* __restrict__ tokens, const int* __restrict__ sel,
    float* __restrict__ out)
{
    const int bid = blockIdx.x;
    const int b = bid / NSLOT, k = bid % NSLOT;
    const int t = threadIdx.x;
    const int kh = k >> 4, kw = k & 15;
    float4* dst4 = (float4*)(out + (long)b * OUTH * IMW * CCH);

    if (k >= NK) {
        const float4 z = {0.f, 0.f, 0.f, 0.f};
        #pragma unroll
        for (int i = 0; i < 16; ++i) {
            int f = i * 256 + t;                 // f4 index within patch 0..4095
            int ti = f >> 9;                     // 512 f4 per (8-col x 256-ch) row
            int off = f & 511;
            long d = ((long)(kh * 8 + ti) * IMW + kw * 8) * (CCH / 4) + off;
            dst4[d] = z;
        }
        return;
    }
    const int p = sel[b * NK + k];
    const int ih = p >> 4, iw = p & 15;
    const float4* src4 = (const float4*)(tokens + (long)b * 16384 * CCH);
    #pragma unroll
    for (int i = 0; i < 16; ++i) {
        int f = i * 256 + t;
        int ti = f >> 9;
        int off = f & 511;
        long srow = ((long)(ih * 8 + ti) * IMW + iw * 8) * (CCH / 4) + off;
        long drow = ((long)(kh * 8 + ti) * IMW + kw * 8) * (CCH / 4) + off;
        dst4[drow] = src4[srow];
    }
}

extern "C" void kernel_launch(void* const* d_in, const int* in_sizes, int n_in,
                              void* d_out, int out_size, void* d_ws, size_t ws_size,
                              hipStream_t stream)
{
    const float* tokens = (const float*)d_in[0];
    const float* W1     = (const float*)d_in[1];
    const float* b1     = (const float*)d_in[2];
    const float* W2     = (const float*)d_in[3];
    const float* b2     = (const float*)d_in[4];
    // d_in[5], d_in[6] are H, W scalars (128, 128) — layout hard-coded.

    const int totalTok = in_sizes[0] / CCH;        // B * 16384
    const int B        = totalTok / (IMW * IMW);   // 16

    int*   sel     = (int*)d_ws;                                    // B*NK ints
    float* tok_imp;
    size_t selBytes = (size_t)B * NK * sizeof(int);
    size_t impBytes = (size_t)totalTok * sizeof(float);
    if (ws_size >= selBytes + 256 + impBytes) {
        tok_imp = (float*)((char*)d_ws + ((selBytes + 255) & ~(size_t)255));
    } else {
        // fall back: use head of d_out as scratch (fully overwritten by gather)
        tok_imp = (float*)d_out;
    }

    scorer_kernel<<<totalTok / MT, 256, 0, stream>>>(tokens, W1, b1, W2, b2, tok_imp);
    select_kernel<<<B, 256, 0, stream>>>(tok_imp, sel);
    gather_kernel<<<B * NSLOT, 256, 0, stream>>>(tokens, sel, (float*)d_out);
}